// Round 4
// baseline (363.694 us; speedup 1.0000x reference)
//
#include <hip/hip_runtime.h>
#include <hip/hip_fp16.h>

#define M_TOK 16384
#define H_DIM 1024
#define F_DIM 4096

typedef __attribute__((ext_vector_type(4))) int int4v;

// ---------------- workspace layout (bytes) ----------------
static const size_t OFF_H2    = 0;                       // fp16 [M,F]  134,217,728
static const size_t OFF_Q2    = OFF_H2   + 134217728ULL; // int8 [M,F]   67,108,864
static const size_t OFF_XQ    = OFF_Q2   + 67108864ULL;  // int8 [M,H]   16,777,216
static const size_t OFF_WQU   = OFF_XQ   + 16777216ULL;  // int8 [F,H]    4,194,304
static const size_t OFF_WQD   = OFF_WQU  + 4194304ULL;   // int8 [H,F]    4,194,304
static const size_t OFF_DQX   = OFF_WQD  + 4194304ULL;   // f32 [M]          65,536
static const size_t OFF_DQ2   = OFF_DQX  + 65536ULL;     // f32 [M]          65,536
static const size_t OFF_PMAX  = OFF_DQ2  + 65536ULL;     // f32 [64,M]    4,194,304
static const size_t OFF_WPART = OFF_PMAX + 4194304ULL;   // f32 [2048]        8,192
static const size_t OFF_WSC   = OFF_WPART+ 8192ULL;      // f32 [4]
static const size_t WS_NEEDED = OFF_WSC  + 16ULL;

__device__ __forceinline__ void ldg_lds16(const void* g, void* l) {
  __builtin_amdgcn_global_load_lds(
      (const __attribute__((address_space(1))) void*)g,
      (__attribute__((address_space(3))) void*)l, 16, 0, 0);
}

// ---------------- K1: |w| partial sums (deterministic) ----------------
__global__ __launch_bounds__(256) void k_wabs(const float* __restrict__ wu,
                                              const float* __restrict__ wd,
                                              float* __restrict__ part) {
  const int b = blockIdx.x;                 // 0..2047 (1024 per tensor)
  const float* w = (b < 1024) ? wu : wd;
  const int cb = b & 1023;
  const size_t base = (size_t)cb * 4096 + threadIdx.x * 4;
  float s = 0.0f;
#pragma unroll
  for (int it = 0; it < 4; ++it) {
    const float4 v = *(const float4*)(w + base + it * 1024);
    s += fabsf(v.x) + fabsf(v.y) + fabsf(v.z) + fabsf(v.w);
  }
#pragma unroll
  for (int sh = 32; sh; sh >>= 1) s += __shfl_xor(s, sh, 64);
  __shared__ float red[4];
  if ((threadIdx.x & 63) == 0) red[threadIdx.x >> 6] = s;
  __syncthreads();
  if (threadIdx.x == 0) part[b] = red[0] + red[1] + red[2] + red[3];
}

// ---------------- K2: finalize per-tensor scale ----------------
__global__ __launch_bounds__(256) void k_wscale(const float* __restrict__ part,
                                                float* __restrict__ wsc) {
  const int b = blockIdx.x;                 // 0: w_up, 1: w_down
  const float* p = part + b * 1024;
  float s = p[threadIdx.x] + p[threadIdx.x + 256] + p[threadIdx.x + 512] + p[threadIdx.x + 768];
#pragma unroll
  for (int sh = 32; sh; sh >>= 1) s += __shfl_xor(s, sh, 64);
  __shared__ float red[4];
  if ((threadIdx.x & 63) == 0) red[threadIdx.x >> 6] = s;
  __syncthreads();
  if (threadIdx.x == 0) {
    const float mean = (red[0] + red[1] + red[2] + red[3]) * (1.0f / 4194304.0f);
    const float c = fmaxf(mean, 1e-5f);
    wsc[b * 2]     = c;         // dequant factor (1/scale)
    wsc[b * 2 + 1] = 1.0f / c;  // scale
  }
}

// ---------------- K3: ternary-quantize both weights ----------------
__global__ __launch_bounds__(256) void k_wquant(const float* __restrict__ wu,
                                                const float* __restrict__ wd,
                                                char* __restrict__ qu,
                                                char* __restrict__ qd,
                                                const float* __restrict__ wsc) {
  const size_t t = (size_t)blockIdx.x * 256 + threadIdx.x;  // 0..2097151
  const float* w; char* q; float scale; size_t i;
  if (t < 1048576) { w = wu; q = qu; scale = wsc[1]; i = t * 4; }
  else             { w = wd; q = qd; scale = wsc[3]; i = (t - 1048576) * 4; }
  const float4 v = *(const float4*)(w + i);
  const int a = (int)rintf(fminf(fmaxf(v.x * scale, -1.0f), 1.0f));
  const int b = (int)rintf(fminf(fmaxf(v.y * scale, -1.0f), 1.0f));
  const int c = (int)rintf(fminf(fmaxf(v.z * scale, -1.0f), 1.0f));
  const int d = (int)rintf(fminf(fmaxf(v.w * scale, -1.0f), 1.0f));
  *(unsigned*)(q + i) = (a & 255) | ((b & 255) << 8) | ((c & 255) << 16) | ((d & 255) << 24);
}

// ---------------- K4: fused RMSNorm + act_quant ----------------
__global__ __launch_bounds__(256) void k_rmsnorm_quant(const float* __restrict__ x,
                                                       const float* __restrict__ nw,
                                                       char* __restrict__ xq,
                                                       float* __restrict__ dqx) {
  const int row = blockIdx.x;
  const int t = threadIdx.x;
  const float4 v = *(const float4*)(x + (size_t)row * H_DIM + t * 4);
  float ss = v.x * v.x + v.y * v.y + v.z * v.z + v.w * v.w;
#pragma unroll
  for (int sh = 32; sh; sh >>= 1) ss += __shfl_xor(ss, sh, 64);
  __shared__ float red[4];
  __shared__ float redm[4];
  if ((t & 63) == 0) red[t >> 6] = ss;
  __syncthreads();
  ss = red[0] + red[1] + red[2] + red[3];
  const float rinv = 1.0f / sqrtf(ss * (1.0f / 1024.0f) + 1e-6f);
  const float4 w4 = *(const float4*)(nw + t * 4);
  float4 n;
  n.x = v.x * rinv * w4.x;  n.y = v.y * rinv * w4.y;
  n.z = v.z * rinv * w4.z;  n.w = v.w * rinv * w4.w;
  float am = fmaxf(fmaxf(fabsf(n.x), fabsf(n.y)), fmaxf(fabsf(n.z), fabsf(n.w)));
#pragma unroll
  for (int sh = 32; sh; sh >>= 1) am = fmaxf(am, __shfl_xor(am, sh, 64));
  if ((t & 63) == 0) redm[t >> 6] = am;
  __syncthreads();
  am = fmaxf(fmaxf(redm[0], redm[1]), fmaxf(redm[2], redm[3]));
  am = fmaxf(am, 1e-5f);
  const float scale = 127.0f / am;
  const int qa = (int)rintf(fminf(fmaxf(n.x * scale, -128.0f), 127.0f));
  const int qb = (int)rintf(fminf(fmaxf(n.y * scale, -128.0f), 127.0f));
  const int qc = (int)rintf(fminf(fmaxf(n.z * scale, -128.0f), 127.0f));
  const int qd = (int)rintf(fminf(fmaxf(n.w * scale, -128.0f), 127.0f));
  *(unsigned*)(xq + (size_t)row * H_DIM + t * 4) =
      (qa & 255) | ((qb & 255) << 8) | ((qc & 255) << 16) | ((qd & 255) << 24);
  if (t == 0) dqx[row] = am * (1.0f / 127.0f);
}

// ---------------- shared int8 GEMM core: 256x256 tile, BK=64, 4-buf ring ----------------
// T3+T4 with the PUBLISH fixed: vmcnt(N) is wave-local, so cross-wave visibility
// of staged LDS data requires  s_waitcnt vmcnt(N)  IMMEDIATELY BEFORE a barrier
// (each wave bounds its own outstanding loads, then the barrier publishes to all).
// Round-3's bug: vmcnt at iteration START, before the wave's own ds_reads of data
// staged by OTHER waves -> unordered.
//
// Tile kt = 64 B of K. LDS buf (kt&3)*32768: A 256x64B at +0, B 256x64B at +16384.
// Seg slot s (16B) of row r holds global k-seg s ^ (r&3): staging DMA lane-linear
// (thread t -> slot t*16), fragment ds_read_b128 bank-uniform.
//
// Schedule (3 barriers/iter; loads never drained to 0 mid-loop):
//   R1: ds_read a0..a3,b0..b3 of buf[kt]; issue A-stage(kt+3)   [depth 3: HBM ~900cy]
//   B1; lgkmcnt(0); setprio(1) 16 MFMA setprio(0)
//   R2: ds_read a4..a7;          issue B-stage(kt+2)            [depth 2: L2 ~200cy]
//   B2; lgkmcnt(0); setprio(1) 16 MFMA setprio(0)
//   vmcnt(tail); B3   <- publishes tile kt+1 to all waves
// FIFO: ...,A(kt+2)@R1(kt-1), B(kt+1)@R2(kt-1), A(kt+3)@R1(kt), B(kt+2)@R2(kt).
// Loads newer than B(kt+1): 2*[kt+3<KT] + 2*[kt+2<KT]  -> tail = 4 / 2 / 0.
// Buffer hazards (regions serialized by barriers): A-half of buf[(kt+3)&3] last
// ds_read in R2(kt-1), lgkm-drained at B2(kt-1) < issue @R1(kt). B-half of
// buf[(kt+2)&3] last read in R1(kt-2), drained at B1(kt-2) << issue @R2(kt).
// Integer accumulation -> bit-identical C regardless of schedule.
template <int LD>
__device__ __forceinline__ void stage_half(const char* g, char* l) {
  ldg_lds16(g, l);                           // rows 0..127 of the 256-row panel
  ldg_lds16(g + (size_t)128 * LD, l + 8192); // rows 128..255
}

#define MFMA_I8(i, j, av, bv) \
  acc[i][j] = __builtin_amdgcn_mfma_i32_16x16x64_i8(av, bv, acc[i][j], 0, 0, 0)

template <int LDA_, int LDB_, int KT>
__device__ __forceinline__ void gemm_core64(const char* __restrict__ A,
                                            const char* __restrict__ B,
                                            int mBase, int nBase,
                                            char* __restrict__ smem,
                                            int4v acc[8][4]) {
  const int t = threadIdx.x;          // 0..511
  const int lane = t & 63;
  const int w = t >> 6;               // wave 0..7
  const int wm = w & 1;               // rows wm*128
  const int wn = w >> 1;              // cols wn*64
  // staging map: thread t fetches row sr, global seg sG into linear slot t*16
  const int sr = t >> 2;              // 0..127
  const int sG = (t & 3) ^ (sr & 3);
  const char* Ag = A + (size_t)(mBase + sr) * LDA_ + sG * 16;
  const char* Bg = B + (size_t)(nBase + sr) * LDB_ + sG * 16;
  // fragment map: global seg q of row r lives at r*64 + ((q^(r&3))<<4); r&3 == fr&3
  const int q  = lane >> 4;
  const int fr = lane & 15;
  const int aoff = ((q ^ (fr & 3)) << 4);
  const int rA = wm * 128 + fr;
  const int rB = wn * 64 + fr;
  char* ldst = smem + (t << 4);

  // prologue in steady-state FIFO order: A0, A1, B0, A2, B1; then publish tile 0.
  // vmcnt(4): newer-than-B0 = {A2, B1} = 4 loads allowed outstanding.
  stage_half<LDA_>(Ag,       ldst);                    // A0 -> buf0
  stage_half<LDA_>(Ag + 64,  ldst + 32768);            // A1 -> buf1
  stage_half<LDB_>(Bg,       ldst + 16384);            // B0 -> buf0
  stage_half<LDA_>(Ag + 128, ldst + 65536);            // A2 -> buf2
  stage_half<LDB_>(Bg + 64,  ldst + 32768 + 16384);    // B1 -> buf1
  asm volatile("s_waitcnt vmcnt(4)" ::: "memory");
  __builtin_amdgcn_s_barrier();

  for (int kt = 0; kt < KT; ++kt) {
    const char* bb = smem + (kt & 3) * 32768;
    // ---- R1: fragments for phase 0 + A-stage of tile kt+3 ----
    int4v a0 = *(const int4v*)(bb + (rA +   0) * 64 + aoff);
    int4v a1 = *(const int4v*)(bb + (rA +  16) * 64 + aoff);
    int4v a2 = *(const int4v*)(bb + (rA +  32) * 64 + aoff);
    int4v a3 = *(const int4v*)(bb + (rA +  48) * 64 + aoff);
    int4v b0 = *(const int4v*)(bb + 16384 + (rB +  0) * 64 + aoff);
    int4v b1 = *(const int4v*)(bb + 16384 + (rB + 16) * 64 + aoff);
    int4v b2 = *(const int4v*)(bb + 16384 + (rB + 32) * 64 + aoff);
    int4v b3 = *(const int4v*)(bb + 16384 + (rB + 48) * 64 + aoff);
    if (kt + 3 < KT)
      stage_half<LDA_>(Ag + (size_t)(kt + 3) * 64,
                       smem + ((kt + 3) & 3) * 32768 + (t << 4));
    __builtin_amdgcn_s_barrier();
    asm volatile("s_waitcnt lgkmcnt(0)" ::: "memory");
    __builtin_amdgcn_sched_barrier(0);
    __builtin_amdgcn_s_setprio(1);
    MFMA_I8(0, 0, a0, b0); MFMA_I8(0, 1, a0, b1); MFMA_I8(0, 2, a0, b2); MFMA_I8(0, 3, a0, b3);
    MFMA_I8(1, 0, a1, b0); MFMA_I8(1, 1, a1, b1); MFMA_I8(1, 2, a1, b2); MFMA_I8(1, 3, a1, b3);
    MFMA_I8(2, 0, a2, b0); MFMA_I8(2, 1, a2, b1); MFMA_I8(2, 2, a2, b2); MFMA_I8(2, 3, a2, b3);
    MFMA_I8(3, 0, a3, b0); MFMA_I8(3, 1, a3, b1); MFMA_I8(3, 2, a3, b2); MFMA_I8(3, 3, a3, b3);
    __builtin_amdgcn_s_setprio(0);
    // ---- R2: fragments for phase 1 (b0..b3 reused) + B-stage of tile kt+2 ----
    a0 = *(const int4v*)(bb + (rA +  64) * 64 + aoff);
    a1 = *(const int4v*)(bb + (rA +  80) * 64 + aoff);
    a2 = *(const int4v*)(bb + (rA +  96) * 64 + aoff);
    a3 = *(const int4v*)(bb + (rA + 112) * 64 + aoff);
    if (kt + 2 < KT)
      stage_half<LDB_>(Bg + (size_t)(kt + 2) * 64,
                       smem + ((kt + 2) & 3) * 32768 + 16384 + (t << 4));
    __builtin_amdgcn_s_barrier();
    asm volatile("s_waitcnt lgkmcnt(0)" ::: "memory");
    __builtin_amdgcn_sched_barrier(0);
    __builtin_amdgcn_s_setprio(1);
    MFMA_I8(4, 0, a0, b0); MFMA_I8(4, 1, a0, b1); MFMA_I8(4, 2, a0, b2); MFMA_I8(4, 3, a0, b3);
    MFMA_I8(5, 0, a1, b0); MFMA_I8(5, 1, a1, b1); MFMA_I8(5, 2, a1, b2); MFMA_I8(5, 3, a1, b3);
    MFMA_I8(6, 0, a2, b0); MFMA_I8(6, 1, a2, b1); MFMA_I8(6, 2, a2, b2); MFMA_I8(6, 3, a2, b3);
    MFMA_I8(7, 0, a3, b0); MFMA_I8(7, 1, a3, b1); MFMA_I8(7, 2, a3, b2); MFMA_I8(7, 3, a3, b3);
    __builtin_amdgcn_s_setprio(0);
    // ---- publish tile kt+1: bound own outstanding loads, THEN barrier ----
    if (kt + 3 < KT)      { asm volatile("s_waitcnt vmcnt(4)" ::: "memory"); }
    else if (kt + 2 < KT) { asm volatile("s_waitcnt vmcnt(2)" ::: "memory"); }
    else                  { asm volatile("s_waitcnt vmcnt(0)" ::: "memory"); }
    __builtin_amdgcn_s_barrier();
  }
}

// ---------------- K5: GEMM1 + relu^2 -> h2(fp16) + row-max partials ----------------
// grid: (x = m-blocks(64), y = n-blocks(16)) — m-fastest for L2 B-panel sharing
__global__ __launch_bounds__(512, 2) void k_gemm1(const char* __restrict__ xq,
                                                  const char* __restrict__ wq,
                                                  const float* __restrict__ wsc,
                                                  const float* __restrict__ dqx,
                                                  __half* __restrict__ h2,
                                                  float* __restrict__ pmax) {
  __shared__ char smem[131072];
  int4v acc[8][4];
#pragma unroll
  for (int i = 0; i < 8; ++i)
#pragma unroll
    for (int j = 0; j < 4; ++j) acc[i][j] = (int4v){0, 0, 0, 0};
  const int mBase = blockIdx.x * 256;
  const int nBase = blockIdx.y * 256;
  gemm_core64<H_DIM, H_DIM, 16>(xq, wq, mBase, nBase, smem, acc);

  const int t = threadIdx.x;
  const int lane = t & 63;
  const int w = t >> 6;
  const int wm = w & 1;
  const int wn = w >> 1;
  const int q  = lane >> 4;
  const int fr = lane & 15;
  const float dqw = wsc[0];
#pragma unroll
  for (int i = 0; i < 8; ++i) {
    const int rbase = mBase + wm * 128 + i * 16 + (q << 2);
    const float4 dq4 = *(const float4*)(dqx + rbase);
    const float* dqp = (const float*)&dq4;
    float rmax[4] = {0.0f, 0.0f, 0.0f, 0.0f};
#pragma unroll
    for (int j = 0; j < 4; ++j) {
      const int col = nBase + wn * 64 + j * 16 + fr;
#pragma unroll
      for (int r = 0; r < 4; ++r) {
        float v = (float)acc[i][j][r] * dqp[r] * dqw;
        v = fmaxf(v, 0.0f);
        v = v * v;
        const __half h = __float2half(v);
        h2[(size_t)(rbase + r) * F_DIM + col] = h;
        rmax[r] = fmaxf(rmax[r], __half2float(h));
      }
    }
#pragma unroll
    for (int s = 1; s < 16; s <<= 1) {
#pragma unroll
      for (int r = 0; r < 4; ++r) rmax[r] = fmaxf(rmax[r], __shfl_xor(rmax[r], s, 64));
    }
    if (fr == 0) {
      const int nb2 = blockIdx.y * 4 + wn;   // 64-col group, 16*4 = 64 groups
#pragma unroll
      for (int r = 0; r < 4; ++r) pmax[(size_t)nb2 * M_TOK + rbase + r] = rmax[r];
    }
  }
}

// ---------------- K5b: fused row-max reduce + quantize h2 -> q2 ----------------
__global__ __launch_bounds__(256) void k_quant2(const __half* __restrict__ h2,
                                                const float* __restrict__ pmax,
                                                char* __restrict__ q2,
                                                float* __restrict__ dq2) {
  const int row = blockIdx.x;
  const int t = threadIdx.x;
  __shared__ float sm;
  if (t < 64) {
    float m = pmax[(size_t)t * M_TOK + row];
#pragma unroll
    for (int sh = 32; sh; sh >>= 1) m = fmaxf(m, __shfl_xor(m, sh, 64));
    if (t == 0) sm = fmaxf(m, 1e-5f);
  }
  __syncthreads();
  const float mx = sm;
  const float s = 127.0f / mx;
  if (t == 0) dq2[row] = mx * (1.0f / 127.0f);
  const size_t i = (size_t)row * F_DIM + t * 16;
  __half2 hh[8];
  *(float4*)(hh)     = *(const float4*)(h2 + i);
  *(float4*)(hh + 4) = *(const float4*)(h2 + i + 8);
  unsigned u[4];
#pragma unroll
  for (int k = 0; k < 4; ++k) {
    const int q0 = (int)rintf(fminf(__low2float(hh[2 * k]) * s, 127.0f));
    const int q1 = (int)rintf(fminf(__high2float(hh[2 * k]) * s, 127.0f));
    const int q2i = (int)rintf(fminf(__low2float(hh[2 * k + 1]) * s, 127.0f));
    const int q3 = (int)rintf(fminf(__high2float(hh[2 * k + 1]) * s, 127.0f));
    u[k] = (q0 & 255) | ((q1 & 255) << 8) | ((q2i & 255) << 16) | ((q3 & 255) << 24);
  }
  *(uint4*)(q2 + i) = make_uint4(u[0], u[1], u[2], u[3]);
}

// ---------------- K6: GEMM2 + dequant + residual ----------------
// grid: (x = m-blocks(64), y = n-blocks(4)) = 256 blocks = 1/CU
__global__ __launch_bounds__(512, 2) void k_gemm2(const char* __restrict__ q2,
                                                  const char* __restrict__ wq,
                                                  const float* __restrict__ wsc,
                                                  const float* __restrict__ dq2,
                                                  const float* __restrict__ x,
                                                  float* __restrict__ out) {
  __shared__ char smem[131072];
  int4v acc[8][4];
#pragma unroll
  for (int i = 0; i < 8; ++i)
#pragma unroll
    for (int j = 0; j < 4; ++j) acc[i][j] = (int4v){0, 0, 0, 0};
  const int mBase = blockIdx.x * 256;
  const int nBase = blockIdx.y * 256;
  gemm_core64<F_DIM, F_DIM, 64>(q2, wq, mBase, nBase, smem, acc);

  const int t = threadIdx.x;
  const int lane = t & 63;
  const int w = t >> 6;
  const int wm = w & 1;
  const int wn = w >> 1;
  const int q  = lane >> 4;
  const int fr = lane & 15;
  const float dqw = wsc[2];
#pragma unroll
  for (int i = 0; i < 8; ++i) {
    const int rbase = mBase + wm * 128 + i * 16 + (q << 2);
    const float4 dq4 = *(const float4*)(dq2 + rbase);
    const float* dqp = (const float*)&dq4;
#pragma unroll
    for (int j = 0; j < 4; ++j) {
      const int col = nBase + wn * 64 + j * 16 + fr;
#pragma unroll
      for (int r = 0; r < 4; ++r) {
        const size_t idx = (size_t)(rbase + r) * H_DIM + col;
        out[idx] = (float)acc[i][j][r] * dqp[r] * dqw + x[idx];
      }
    }
  }
}

extern "C" void kernel_launch(void* const* d_in, const int* in_sizes, int n_in,
                              void* d_out, int out_size, void* d_ws, size_t ws_size,
                              hipStream_t stream) {
  const float* x  = (const float*)d_in[0];
  const float* nw = (const float*)d_in[1];
  const float* wu = (const float*)d_in[2];
  const float* wd = (const float*)d_in[3];
  float* out = (float*)d_out;
  char* ws = (char*)d_ws;
  if (ws_size < WS_NEEDED) return;  // workspace too small: leave output poisoned (diagnostic)

  __half* h2     = (__half*)(ws + OFF_H2);
  char* q2       = ws + OFF_Q2;
  char* xq       = ws + OFF_XQ;
  char* wqu      = ws + OFF_WQU;
  char* wqd      = ws + OFF_WQD;
  float* dqx     = (float*)(ws + OFF_DQX);
  float* dq2     = (float*)(ws + OFF_DQ2);
  float* pmax    = (float*)(ws + OFF_PMAX);
  float* wpart   = (float*)(ws + OFF_WPART);
  float* wsc     = (float*)(ws + OFF_WSC);

  k_wabs<<<2048, 256, 0, stream>>>(wu, wd, wpart);
  k_wscale<<<2, 256, 0, stream>>>(wpart, wsc);
  k_wquant<<<8192, 256, 0, stream>>>(wu, wd, wqu, wqd, wsc);
  k_rmsnorm_quant<<<M_TOK, 256, 0, stream>>>(x, nw, xq, dqx);
  k_gemm1<<<dim3(M_TOK / 256, F_DIM / 256), 512, 0, stream>>>(xq, wqu, wsc, dqx, h2, pmax);
  k_quant2<<<M_TOK, 256, 0, stream>>>(h2, pmax, q2, dq2);
  k_gemm2<<<dim3(M_TOK / 256, H_DIM / 256), 512, 0, stream>>>(q2, wqd, wsc, dq2, x, out);
}

// Round 5
// 333.778 us; speedup vs baseline: 1.0896x; 1.0896x over previous
//
#include <hip/hip_runtime.h>
#include <hip/hip_fp16.h>

#define M_TOK 16384
#define H_DIM 1024
#define F_DIM 4096

typedef __attribute__((ext_vector_type(4))) int int4v;

// ---------------- workspace layout (bytes) ----------------
static const size_t OFF_H2    = 0;                       // fp16 [M,F]  134,217,728
static const size_t OFF_Q2    = OFF_H2   + 134217728ULL; // int8 [M,F]   67,108,864
static const size_t OFF_XQ    = OFF_Q2   + 67108864ULL;  // int8 [M,H]   16,777,216
static const size_t OFF_WQU   = OFF_XQ   + 16777216ULL;  // int8 [F,H]    4,194,304
static const size_t OFF_WQD   = OFF_WQU  + 4194304ULL;   // int8 [H,F]    4,194,304
static const size_t OFF_DQX   = OFF_WQD  + 4194304ULL;   // f32 [M]          65,536
static const size_t OFF_DQ2   = OFF_DQX  + 65536ULL;     // f32 [M]          65,536
static const size_t OFF_PMAX  = OFF_DQ2  + 65536ULL;     // f32 [64,M]    4,194,304
static const size_t OFF_WPART = OFF_PMAX + 4194304ULL;   // f32 [2048]        8,192
static const size_t OFF_WSC   = OFF_WPART+ 8192ULL;      // f32 [4]
static const size_t WS_NEEDED = OFF_WSC  + 16ULL;

__device__ __forceinline__ void ldg_lds16(const void* g, void* l) {
  __builtin_amdgcn_global_load_lds(
      (const __attribute__((address_space(1))) void*)g,
      (__attribute__((address_space(3))) void*)l, 16, 0, 0);
}

// ---------------- K1: |w| partial sums (deterministic) ----------------
__global__ __launch_bounds__(256) void k_wabs(const float* __restrict__ wu,
                                              const float* __restrict__ wd,
                                              float* __restrict__ part) {
  const int b = blockIdx.x;                 // 0..2047 (1024 per tensor)
  const float* w = (b < 1024) ? wu : wd;
  const int cb = b & 1023;
  const size_t base = (size_t)cb * 4096 + threadIdx.x * 4;
  float s = 0.0f;
#pragma unroll
  for (int it = 0; it < 4; ++it) {
    const float4 v = *(const float4*)(w + base + it * 1024);
    s += fabsf(v.x) + fabsf(v.y) + fabsf(v.z) + fabsf(v.w);
  }
#pragma unroll
  for (int sh = 32; sh; sh >>= 1) s += __shfl_xor(s, sh, 64);
  __shared__ float red[4];
  if ((threadIdx.x & 63) == 0) red[threadIdx.x >> 6] = s;
  __syncthreads();
  if (threadIdx.x == 0) part[b] = red[0] + red[1] + red[2] + red[3];
}

// ---------------- K2: finalize per-tensor scale ----------------
__global__ __launch_bounds__(256) void k_wscale(const float* __restrict__ part,
                                                float* __restrict__ wsc) {
  const int b = blockIdx.x;                 // 0: w_up, 1: w_down
  const float* p = part + b * 1024;
  float s = p[threadIdx.x] + p[threadIdx.x + 256] + p[threadIdx.x + 512] + p[threadIdx.x + 768];
#pragma unroll
  for (int sh = 32; sh; sh >>= 1) s += __shfl_xor(s, sh, 64);
  __shared__ float red[4];
  if ((threadIdx.x & 63) == 0) red[threadIdx.x >> 6] = s;
  __syncthreads();
  if (threadIdx.x == 0) {
    const float mean = (red[0] + red[1] + red[2] + red[3]) * (1.0f / 4194304.0f);
    const float c = fmaxf(mean, 1e-5f);
    wsc[b * 2]     = c;         // dequant factor (1/scale)
    wsc[b * 2 + 1] = 1.0f / c;  // scale
  }
}

// ---------------- K3: ternary-quantize both weights ----------------
__global__ __launch_bounds__(256) void k_wquant(const float* __restrict__ wu,
                                                const float* __restrict__ wd,
                                                char* __restrict__ qu,
                                                char* __restrict__ qd,
                                                const float* __restrict__ wsc) {
  const size_t t = (size_t)blockIdx.x * 256 + threadIdx.x;  // 0..2097151
  const float* w; char* q; float scale; size_t i;
  if (t < 1048576) { w = wu; q = qu; scale = wsc[1]; i = t * 4; }
  else             { w = wd; q = qd; scale = wsc[3]; i = (t - 1048576) * 4; }
  const float4 v = *(const float4*)(w + i);
  const int a = (int)rintf(fminf(fmaxf(v.x * scale, -1.0f), 1.0f));
  const int b = (int)rintf(fminf(fmaxf(v.y * scale, -1.0f), 1.0f));
  const int c = (int)rintf(fminf(fmaxf(v.z * scale, -1.0f), 1.0f));
  const int d = (int)rintf(fminf(fmaxf(v.w * scale, -1.0f), 1.0f));
  *(unsigned*)(q + i) = (a & 255) | ((b & 255) << 8) | ((c & 255) << 16) | ((d & 255) << 24);
}

// ---------------- K4: fused RMSNorm + act_quant ----------------
__global__ __launch_bounds__(256) void k_rmsnorm_quant(const float* __restrict__ x,
                                                       const float* __restrict__ nw,
                                                       char* __restrict__ xq,
                                                       float* __restrict__ dqx) {
  const int row = blockIdx.x;
  const int t = threadIdx.x;
  const float4 v = *(const float4*)(x + (size_t)row * H_DIM + t * 4);
  float ss = v.x * v.x + v.y * v.y + v.z * v.z + v.w * v.w;
#pragma unroll
  for (int sh = 32; sh; sh >>= 1) ss += __shfl_xor(ss, sh, 64);
  __shared__ float red[4];
  __shared__ float redm[4];
  if ((t & 63) == 0) red[t >> 6] = ss;
  __syncthreads();
  ss = red[0] + red[1] + red[2] + red[3];
  const float rinv = 1.0f / sqrtf(ss * (1.0f / 1024.0f) + 1e-6f);
  const float4 w4 = *(const float4*)(nw + t * 4);
  float4 n;
  n.x = v.x * rinv * w4.x;  n.y = v.y * rinv * w4.y;
  n.z = v.z * rinv * w4.z;  n.w = v.w * rinv * w4.w;
  float am = fmaxf(fmaxf(fabsf(n.x), fabsf(n.y)), fmaxf(fabsf(n.z), fabsf(n.w)));
#pragma unroll
  for (int sh = 32; sh; sh >>= 1) am = fmaxf(am, __shfl_xor(am, sh, 64));
  if ((t & 63) == 0) redm[t >> 6] = am;
  __syncthreads();
  am = fmaxf(fmaxf(redm[0], redm[1]), fmaxf(redm[2], redm[3]));
  am = fmaxf(am, 1e-5f);
  const float scale = 127.0f / am;
  const int qa = (int)rintf(fminf(fmaxf(n.x * scale, -128.0f), 127.0f));
  const int qb = (int)rintf(fminf(fmaxf(n.y * scale, -128.0f), 127.0f));
  const int qc = (int)rintf(fminf(fmaxf(n.z * scale, -128.0f), 127.0f));
  const int qd = (int)rintf(fminf(fmaxf(n.w * scale, -128.0f), 127.0f));
  *(unsigned*)(xq + (size_t)row * H_DIM + t * 4) =
      (qa & 255) | ((qb & 255) << 8) | ((qc & 255) << 16) | ((qd & 255) << 24);
  if (t == 0) dqx[row] = am * (1.0f / 127.0f);
}

// ---------------- shared int8 GEMM core: 256x256, BK=128, 4-phase counted ----------------
// Layout = round-2's PROVEN conflict-free one (0 bank conflicts measured):
// buffer p at p*65536: A 256 rows x 128B at +0, B at +32768. Seg slot s of row r
// holds global k-seg s ^ (r&7); ds_read slot (ks*4+q)^(fr&7) -> 8 consecutive
// lanes cover 8 distinct 16B slots per 128B stripe (conflict-free), staging DMA
// lane-linear (thread t -> slot t*16 within each 64-row 8KB quarter).
//
// Schedule: 4 phases/tile, 16 MFMA each, LDS reads 8/4/8/4. Staging = 8 quarter
// units/tile (1 gload_lds/thread each), B quarters early, A quarters late:
//   P0(ks0,i0-3): reads a0-3,b0-3; stage Bq0,Bq1(kt+1); MFMA;
//                 vmcnt(2|0 last tile) + s_barrier   <- publishes Aq1,Aq3(kt)
//   P1(ks0,i4-7): reads a4-7;       stage Bq2,Bq3(kt+1); MFMA
//   P2(ks1,i0-3): reads a0-3,b0-3;  stage Aq0,Aq2(kt+1); MFMA
//   P3(ks1,i4-7): reads a4-7;       stage Aq1,Aq3(kt+1); MFMA;
//                 vmcnt(2) + s_barrier   <- publishes tile kt+1 minus Aq1,Aq3
// FIFO: end-P3 has 8 outstanding -> vmcnt(2) lands all B + Aq0,Aq2 of kt+1;
// end-P0 has [Aq13(kt), Bq01(kt+1)] = 4 -> vmcnt(2) lands Aq13(kt). Loads are
// never drained to 0 mid-loop (T4). Only 2 barriers/tile; phases P1-P3 have no
// barrier -> waves skew so one wave's ds_reads overlap another's MFMAs (the
// LDS-port/MFMA-pipe serialization that capped round 2 at 31% MfmaUtil).
// Buffer-reuse hazards: every overwritten quarter's last ds_read (tile kt-1)
// completes (lgkm before its consumer MFMA) before that wave reaches the
// end-P3(kt-1) barrier, which precedes all tile-(kt+1) staging. Reads target
// cur, stages target nxt -> skew inside P1..P3 is hazard-free.
// vmcnt is wave-local: each publish bounds own loads THEN barriers (all waves'
// loads counted at the same point => staged data globally visible).
// Int32 accumulation, per-element K-order unchanged -> bit-identical C.
#define MFMA_I8(i, j, av, bv) \
  acc[i][j] = __builtin_amdgcn_mfma_i32_16x16x64_i8(av, bv, acc[i][j], 0, 0, 0)

#define MFMA16(IB) \
  __builtin_amdgcn_s_setprio(1); \
  MFMA_I8(IB + 0, 0, a0, b0); MFMA_I8(IB + 0, 1, a0, b1); MFMA_I8(IB + 0, 2, a0, b2); MFMA_I8(IB + 0, 3, a0, b3); \
  MFMA_I8(IB + 1, 0, a1, b0); MFMA_I8(IB + 1, 1, a1, b1); MFMA_I8(IB + 1, 2, a1, b2); MFMA_I8(IB + 1, 3, a1, b3); \
  MFMA_I8(IB + 2, 0, a2, b0); MFMA_I8(IB + 2, 1, a2, b1); MFMA_I8(IB + 2, 2, a2, b2); MFMA_I8(IB + 2, 3, a2, b3); \
  MFMA_I8(IB + 3, 0, a3, b0); MFMA_I8(IB + 3, 1, a3, b1); MFMA_I8(IB + 3, 2, a3, b2); MFMA_I8(IB + 3, 3, a3, b3); \
  __builtin_amdgcn_s_setprio(0)

template <int LDA_, int LDB_, int KT>
__device__ __forceinline__ void gemm_core4p(const char* __restrict__ A,
                                            const char* __restrict__ B,
                                            int mBase, int nBase,
                                            char* __restrict__ smem,
                                            int4v acc[8][4]) {
  const int t = threadIdx.x;          // 0..511
  const int lane = t & 63;
  const int w = t >> 6;               // wave 0..7
  const int wm = w & 1;               // rows wm*128
  const int wn = w >> 1;              // cols wn*64
  // staging map: thread t -> row-in-quarter sRow=t>>3, swizzled k-seg sSeg
  const int sRow = t >> 3;            // 0..63
  const int sSeg = (t & 7) ^ (sRow & 7);
  const char* Ag = A + (size_t)(mBase + sRow) * LDA_ + sSeg * 16;
  const char* Bg = B + (size_t)(nBase + sRow) * LDB_ + sSeg * 16;
  // fragment map
  const int q  = lane >> 4;
  const int fr = lane & 15;
  const int sw = fr & 7;
  const int s0 = ((q) ^ sw) << 4;       // ks=0 slot
  const int s1 = ((4 + q) ^ sw) << 4;   // ks=1 slot
  const int rA = wm * 128 + fr;
  const int rB = wn * 64 + fr;
  const int dst = t << 4;             // linear LDS slot within an 8KB quarter

  // quarter stage helpers (Q*64 rows source offset; Q*8192 LDS offset)
#define STG_A(Q, KTI, BUFO) \
  ldg_lds16(Ag + (size_t)((Q) * 64) * LDA_ + (size_t)(KTI) * 128, \
            smem + (BUFO) + (Q) * 8192 + dst)
#define STG_B(Q, KTI, BUFO) \
  ldg_lds16(Bg + (size_t)((Q) * 64) * LDB_ + (size_t)(KTI) * 128, \
            smem + (BUFO) + 32768 + (Q) * 8192 + dst)

  // prologue: tile 0 in steady-state FIFO order (B first, Aq02, Aq13 last)
  STG_B(0, 0, 0); STG_B(1, 0, 0); STG_B(2, 0, 0); STG_B(3, 0, 0);
  STG_A(0, 0, 0); STG_A(2, 0, 0); STG_A(1, 0, 0); STG_A(3, 0, 0);
  asm volatile("s_waitcnt vmcnt(2)\n\ts_barrier" ::: "memory");

  int cur = 0;
  for (int kt = 0; kt < KT; ++kt) {
    const int nxt = cur ^ 65536;
    const char* Ab = smem + cur;
    const char* Bb = smem + cur + 32768;
    int4v a0, a1, a2, a3, b0, b1, b2, b3;
    // ---- P0: ks=0, i=0..3 ----
    a0 = *(const int4v*)(Ab + (rA +  0) * 128 + s0);
    a1 = *(const int4v*)(Ab + (rA + 16) * 128 + s0);
    a2 = *(const int4v*)(Ab + (rA + 32) * 128 + s0);
    a3 = *(const int4v*)(Ab + (rA + 48) * 128 + s0);
    b0 = *(const int4v*)(Bb + (rB +  0) * 128 + s0);
    b1 = *(const int4v*)(Bb + (rB + 16) * 128 + s0);
    b2 = *(const int4v*)(Bb + (rB + 32) * 128 + s0);
    b3 = *(const int4v*)(Bb + (rB + 48) * 128 + s0);
    if (kt + 1 < KT) { STG_B(0, kt + 1, nxt); STG_B(1, kt + 1, nxt); }
    MFMA16(0);
    if (kt + 1 < KT) { asm volatile("s_waitcnt vmcnt(2)\n\ts_barrier" ::: "memory"); }
    else             { asm volatile("s_waitcnt vmcnt(0)\n\ts_barrier" ::: "memory"); }
    // ---- P1: ks=0, i=4..7 ----
    a0 = *(const int4v*)(Ab + (rA +  64) * 128 + s0);
    a1 = *(const int4v*)(Ab + (rA +  80) * 128 + s0);
    a2 = *(const int4v*)(Ab + (rA +  96) * 128 + s0);
    a3 = *(const int4v*)(Ab + (rA + 112) * 128 + s0);
    if (kt + 1 < KT) { STG_B(2, kt + 1, nxt); STG_B(3, kt + 1, nxt); }
    MFMA16(4);
    // ---- P2: ks=1, i=0..3 ----
    a0 = *(const int4v*)(Ab + (rA +  0) * 128 + s1);
    a1 = *(const int4v*)(Ab + (rA + 16) * 128 + s1);
    a2 = *(const int4v*)(Ab + (rA + 32) * 128 + s1);
    a3 = *(const int4v*)(Ab + (rA + 48) * 128 + s1);
    b0 = *(const int4v*)(Bb + (rB +  0) * 128 + s1);
    b1 = *(const int4v*)(Bb + (rB + 16) * 128 + s1);
    b2 = *(const int4v*)(Bb + (rB + 32) * 128 + s1);
    b3 = *(const int4v*)(Bb + (rB + 48) * 128 + s1);
    if (kt + 1 < KT) { STG_A(0, kt + 1, nxt); STG_A(2, kt + 1, nxt); }
    MFMA16(0);
    // ---- P3: ks=1, i=4..7 ----
    a0 = *(const int4v*)(Ab + (rA +  64) * 128 + s1);
    a1 = *(const int4v*)(Ab + (rA +  80) * 128 + s1);
    a2 = *(const int4v*)(Ab + (rA +  96) * 128 + s1);
    a3 = *(const int4v*)(Ab + (rA + 112) * 128 + s1);
    if (kt + 1 < KT) { STG_A(1, kt + 1, nxt); STG_A(3, kt + 1, nxt); }
    MFMA16(4);
    asm volatile("s_waitcnt vmcnt(2)\n\ts_barrier" ::: "memory");
    cur = nxt;
  }
#undef STG_A
#undef STG_B
}

// ---------------- K5: GEMM1 + relu^2 -> h2(fp16) + row-max partials ----------------
// grid: (x = m-blocks(64), y = n-blocks(16)) — m-fastest for L2 B-panel sharing
__global__ __launch_bounds__(512, 2) void k_gemm1(const char* __restrict__ xq,
                                                  const char* __restrict__ wq,
                                                  const float* __restrict__ wsc,
                                                  const float* __restrict__ dqx,
                                                  __half* __restrict__ h2,
                                                  float* __restrict__ pmax) {
  __shared__ char smem[131072];
  int4v acc[8][4];
#pragma unroll
  for (int i = 0; i < 8; ++i)
#pragma unroll
    for (int j = 0; j < 4; ++j) acc[i][j] = (int4v){0, 0, 0, 0};
  const int mBase = blockIdx.x * 256;
  const int nBase = blockIdx.y * 256;
  gemm_core4p<H_DIM, H_DIM, 8>(xq, wq, mBase, nBase, smem, acc);

  const int t = threadIdx.x;
  const int lane = t & 63;
  const int w = t >> 6;
  const int wm = w & 1;
  const int wn = w >> 1;
  const int q  = lane >> 4;
  const int fr = lane & 15;
  const float dqw = wsc[0];
#pragma unroll
  for (int i = 0; i < 8; ++i) {
    const int rbase = mBase + wm * 128 + i * 16 + (q << 2);
    const float4 dq4 = *(const float4*)(dqx + rbase);
    const float* dqp = (const float*)&dq4;
    float rmax[4] = {0.0f, 0.0f, 0.0f, 0.0f};
#pragma unroll
    for (int j = 0; j < 4; ++j) {
      const int col = nBase + wn * 64 + j * 16 + fr;
#pragma unroll
      for (int r = 0; r < 4; ++r) {
        float v = (float)acc[i][j][r] * dqp[r] * dqw;
        v = fmaxf(v, 0.0f);
        v = v * v;
        const __half h = __float2half(v);
        h2[(size_t)(rbase + r) * F_DIM + col] = h;
        rmax[r] = fmaxf(rmax[r], __half2float(h));
      }
    }
#pragma unroll
    for (int s = 1; s < 16; s <<= 1) {
#pragma unroll
      for (int r = 0; r < 4; ++r) rmax[r] = fmaxf(rmax[r], __shfl_xor(rmax[r], s, 64));
    }
    if (fr == 0) {
      const int nb2 = blockIdx.y * 4 + wn;   // 64-col group, 16*4 = 64 groups
#pragma unroll
      for (int r = 0; r < 4; ++r) pmax[(size_t)nb2 * M_TOK + rbase + r] = rmax[r];
    }
  }
}

// ---------------- K5b: fused row-max reduce + quantize h2 -> q2 ----------------
__global__ __launch_bounds__(256) void k_quant2(const __half* __restrict__ h2,
                                                const float* __restrict__ pmax,
                                                char* __restrict__ q2,
                                                float* __restrict__ dq2) {
  const int row = blockIdx.x;
  const int t = threadIdx.x;
  __shared__ float sm;
  if (t < 64) {
    float m = pmax[(size_t)t * M_TOK + row];
#pragma unroll
    for (int sh = 32; sh; sh >>= 1) m = fmaxf(m, __shfl_xor(m, sh, 64));
    if (t == 0) sm = fmaxf(m, 1e-5f);
  }
  __syncthreads();
  const float mx = sm;
  const float s = 127.0f / mx;
  if (t == 0) dq2[row] = mx * (1.0f / 127.0f);
  const size_t i = (size_t)row * F_DIM + t * 16;
  __half2 hh[8];
  *(float4*)(hh)     = *(const float4*)(h2 + i);
  *(float4*)(hh + 4) = *(const float4*)(h2 + i + 8);
  unsigned u[4];
#pragma unroll
  for (int k = 0; k < 4; ++k) {
    const int q0 = (int)rintf(fminf(__low2float(hh[2 * k]) * s, 127.0f));
    const int q1 = (int)rintf(fminf(__high2float(hh[2 * k]) * s, 127.0f));
    const int q2i = (int)rintf(fminf(__low2float(hh[2 * k + 1]) * s, 127.0f));
    const int q3 = (int)rintf(fminf(__high2float(hh[2 * k + 1]) * s, 127.0f));
    u[k] = (q0 & 255) | ((q1 & 255) << 8) | ((q2i & 255) << 16) | ((q3 & 255) << 24);
  }
  *(uint4*)(q2 + i) = make_uint4(u[0], u[1], u[2], u[3]);
}

// ---------------- K6: GEMM2 + dequant + residual ----------------
// grid: (x = m-blocks(64), y = n-blocks(4)) = 256 blocks = 1/CU
__global__ __launch_bounds__(512, 2) void k_gemm2(const char* __restrict__ q2,
                                                  const char* __restrict__ wq,
                                                  const float* __restrict__ wsc,
                                                  const float* __restrict__ dq2,
                                                  const float* __restrict__ x,
                                                  float* __restrict__ out) {
  __shared__ char smem[131072];
  int4v acc[8][4];
#pragma unroll
  for (int i = 0; i < 8; ++i)
#pragma unroll
    for (int j = 0; j < 4; ++j) acc[i][j] = (int4v){0, 0, 0, 0};
  const int mBase = blockIdx.x * 256;
  const int nBase = blockIdx.y * 256;
  gemm_core4p<F_DIM, F_DIM, 32>(q2, wq, mBase, nBase, smem, acc);

  const int t = threadIdx.x;
  const int lane = t & 63;
  const int w = t >> 6;
  const int wm = w & 1;
  const int wn = w >> 1;
  const int q  = lane >> 4;
  const int fr = lane & 15;
  const float dqw = wsc[2];
#pragma unroll
  for (int i = 0; i < 8; ++i) {
    const int rbase = mBase + wm * 128 + i * 16 + (q << 2);
    const float4 dq4 = *(const float4*)(dq2 + rbase);
    const float* dqp = (const float*)&dq4;
#pragma unroll
    for (int j = 0; j < 4; ++j) {
      const int col = nBase + wn * 64 + j * 16 + fr;
#pragma unroll
      for (int r = 0; r < 4; ++r) {
        const size_t idx = (size_t)(rbase + r) * H_DIM + col;
        out[idx] = (float)acc[i][j][r] * dqp[r] * dqw + x[idx];
      }
    }
  }
}

extern "C" void kernel_launch(void* const* d_in, const int* in_sizes, int n_in,
                              void* d_out, int out_size, void* d_ws, size_t ws_size,
                              hipStream_t stream) {
  const float* x  = (const float*)d_in[0];
  const float* nw = (const float*)d_in[1];
  const float* wu = (const float*)d_in[2];
  const float* wd = (const float*)d_in[3];
  float* out = (float*)d_out;
  char* ws = (char*)d_ws;
  if (ws_size < WS_NEEDED) return;  // workspace too small: leave output poisoned (diagnostic)

  __half* h2     = (__half*)(ws + OFF_H2);
  char* q2       = ws + OFF_Q2;
  char* xq       = ws + OFF_XQ;
  char* wqu      = ws + OFF_WQU;
  char* wqd      = ws + OFF_WQD;
  float* dqx     = (float*)(ws + OFF_DQX);
  float* dq2     = (float*)(ws + OFF_DQ2);
  float* pmax    = (float*)(ws + OFF_PMAX);
  float* wpart   = (float*)(ws + OFF_WPART);
  float* wsc     = (float*)(ws + OFF_WSC);

  k_wabs<<<2048, 256, 0, stream>>>(wu, wd, wpart);
  k_wscale<<<2, 256, 0, stream>>>(wpart, wsc);
  k_wquant<<<8192, 256, 0, stream>>>(wu, wd, wqu, wqd, wsc);
  k_rmsnorm_quant<<<M_TOK, 256, 0, stream>>>(x, nw, xq, dqx);
  k_gemm1<<<dim3(M_TOK / 256, F_DIM / 256), 512, 0, stream>>>(xq, wqu, wsc, dqx, h2, pmax);
  k_quant2<<<M_TOK, 256, 0, stream>>>(h2, pmax, q2, dq2);
  k_gemm2<<<dim3(M_TOK / 256, H_DIM / 256), 512, 0, stream>>>(q2, wqd, wsc, dq2, x, out);
}